// Round 2
// baseline (79.106 us; speedup 1.0000x reference)
//
#include <hip/hip_runtime.h>

#define NINST 64
#define ACC_STRIDE 512   // floats per image in accumulator region
// per-image acc layout:
//  [0,64)    counts
//  [64,256)  sum3  (k*3+c)
//  [256,320) h255 segment sums
//  [320]     h0 (label-0 huber-to-0 sum)
#define OFF_CNT  0
#define OFF_SUM  64
#define OFF_H255 256
#define OFF_H0   320
#define LAMBDA_SEP 300.0f

#define P1_GX 192        // pass1 grid.x (768 blocks = 3/CU; LDS 3x47.6KB fits 160KB)
#define P1_THREADS 512
#define P1_WAVES (P1_THREADS / 64)
#define P2_GX 128        // pass2-role blocks per image (1024 threads)
#define P23_THREADS 1024
#define P3B 8            // pass3-role blocks per image
#define P3_TILE 1024     // bg pixels staged per pass3 tile (16 waves x 64)
#define CNT_STRIDE 64    // uints between per-image bg counters (256B)
#define BGBUF 512        // per-block LDS bg staging capacity (mean ~50/block)

__device__ __forceinline__ float huber1(float x, float c) {
    float d = fabsf(x - c);
    return d < 1.0f ? 0.5f * d * d : d - 0.5f;
}

// Pass 1 (grouped broadcast + register prefetch): segment sums, 8 px per LDS read.
// Wave = 8 groups x 8 lanes; group g reads staged slot j*8+g (conflict-free);
// lane sub-index s owns bins 8s..8s+7 in 32 VGPR accumulators.
// Global loads for iteration k+1 are issued before iteration k's compute
// (register double-buffer) so L2/HBM latency hides under ~3K cycles of VALU.
// grid = (P1_GX, B), 512 threads.
__global__ __launch_bounds__(P1_THREADS, 4)
void k_pass1(const float* __restrict__ pred, const float* __restrict__ targ,
             float* __restrict__ acc, unsigned* __restrict__ bgcnt,
             float* __restrict__ bglist, int maxbg, int N) {
    __shared__ float4 s_stage[P1_WAVES][256];   // wave-private pixel staging (reused for reduce)
    __shared__ float4 s_red[P1_WAVES][NINST];   // per-wave per-bin (cnt,sx,sy,sz)
    __shared__ float s_corr255[NINST];
    __shared__ float s_corr0;
    __shared__ float s_bgbuf[BGBUF * 3];
    __shared__ unsigned s_bgn;
    __shared__ unsigned s_base;
    int tid = threadIdx.x;
    int lane = tid & 63;
    int wv = tid >> 6;
    int grp = lane >> 3;           // which staged pixel column this lane reads
    int s8 = (lane & 7) << 3;      // lane's bin base (bins s8..s8+7)
    if (tid < NINST) s_corr255[tid] = 0.0f;
    if (tid == 0) { s_corr0 = 0.0f; s_bgn = 0u; }
    __syncthreads();

    int b = blockIdx.y;
    const float* bp = pred + (size_t)b * 3 * N;
    const float* bt = targ + (size_t)b * 3 * N;
    const float4* t0 = (const float4*)bt;
    const float4* p0 = (const float4*)bp;
    const float4* p1 = (const float4*)(bp + N);
    const float4* p2 = (const float4*)(bp + 2 * N);
    unsigned* bgc = &bgcnt[(size_t)b * CNT_STRIDE];
    float* bgl = bglist + (size_t)b * maxbg * 3;
    float* g = acc + (size_t)b * ACC_STRIDE;

    float cnt[8], sx[8], sy[8], sz[8];   // lane's 8 bins: s8..s8+7
#pragma unroll
    for (int t = 0; t < 8; t++) { cnt[t] = 0.0f; sx[t] = 0.0f; sy[t] = 0.0f; sz[t] = 0.0f; }

    int M = N >> 2;
    int stride = gridDim.x * blockDim.x;
    int base = blockIdx.x * blockDim.x + wv * 64;   // wave's first quad index

    // prefetch iteration 0
    float4 ct = make_float4(0, 0, 0, 0), ca = ct, cc = ct, cd = ct;
    if (base < M) {
        int i = base + lane;
        if (i < M) { ct = t0[i]; ca = p0[i]; cc = p1[i]; cd = p2[i]; }
    }

    for (; base < M;) {
        int i = base + lane;
        bool valid = i < M;
        // issue next iteration's loads NOW; vmcnt-wait lands after this
        // iteration's staging+accumulate (~3K cycles of cover)
        int nbase = base + stride;
        float4 nt = make_float4(0, 0, 0, 0), na = nt, nc = nt, nd = nt;
        if (nbase < M) {
            int ni = nbase + lane;
            if (ni < M) { nt = t0[ni]; na = p0[ni]; nc = p1[ni]; nd = p2[ni]; }
        }

        float xx[4], yy[4], zz[4];
        int labs[4];
        if (valid) {
            float tt[4] = {ct.x, ct.y, ct.z, ct.w};
            xx[0] = ca.x; xx[1] = ca.y; xx[2] = ca.z; xx[3] = ca.w;
            yy[0] = cc.x; yy[1] = cc.y; yy[2] = cc.z; yy[3] = cc.w;
            zz[0] = cd.x; zz[1] = cd.y; zz[2] = cd.z; zz[3] = cd.w;
#pragma unroll
            for (int j = 0; j < 4; j++) {
                int lab = (int)(tt[j] * 0.25f + 0.5f);   // exact: labels are multiples of 4
                labs[j] = lab;
                // rare huber corrections (channel within 1 of the constant)
                float dx = 255.0f - xx[j], dy = 255.0f - yy[j], dz = 255.0f - zz[j];
                float corr = 0.0f;
                if (dx < 1.0f) { float e = 1.0f - dx; corr += 0.5f * e * e; }
                if (dy < 1.0f) { float e = 1.0f - dy; corr += 0.5f * e * e; }
                if (dz < 1.0f) { float e = 1.0f - dz; corr += 0.5f * e * e; }
                if (corr != 0.0f) atomicAdd(&s_corr255[lab], corr);
                if (lab == 0) {
                    float c0 = 0.0f;
                    if (xx[j] < 1.0f) { float e = 1.0f - xx[j]; c0 += 0.5f * e * e; }
                    if (yy[j] < 1.0f) { float e = 1.0f - yy[j]; c0 += 0.5f * e * e; }
                    if (zz[j] < 1.0f) { float e = 1.0f - zz[j]; c0 += 0.5f * e * e; }
                    if (c0 != 0.0f) atomicAdd(&s_corr0, c0);
                    unsigned idx = atomicAdd(&s_bgn, 1u);       // rare (~1.6% of px)
                    if (idx < BGBUF) {
                        s_bgbuf[idx * 3 + 0] = xx[j];
                        s_bgbuf[idx * 3 + 1] = yy[j];
                        s_bgbuf[idx * 3 + 2] = zz[j];
                    } else {
                        unsigned gi = atomicAdd(bgc, 1u);
                        if ((int)gi < maxbg) {
                            bgl[(size_t)gi * 3 + 0] = xx[j];
                            bgl[(size_t)gi * 3 + 1] = yy[j];
                            bgl[(size_t)gi * 3 + 2] = zz[j];
                        }
                    }
                }
            }
        } else {
#pragma unroll
            for (int j = 0; j < 4; j++) { xx[j] = yy[j] = zz[j] = 0.0f; labs[j] = -1; }
        }
        // stage 4 pixels: slot j*64+lane -> contiguous 16B per lane (conflict-free)
#pragma unroll
        for (int j = 0; j < 4; j++)
            s_stage[wv][j * 64 + lane] =
                make_float4(xx[j], yy[j], zz[j], __int_as_float(labs[j]));
        // grouped broadcast accumulate: one ds_read_b128 retires 8 pixels.
#pragma unroll 4
        for (int j = 0; j < 32; j++) {
            float4 v = s_stage[wv][(j << 3) + grp];
            int rel = __float_as_int(v.w) - s8;      // in [0,8) iff pixel is in lane's bins
#pragma unroll
            for (int t = 0; t < 8; t++) {
                float m = (rel == t) ? 1.0f : 0.0f;
                cnt[t] += m;
                sx[t] = fmaf(m, v.x, sx[t]);
                sy[t] = fmaf(m, v.y, sy[t]);
                sz[t] = fmaf(m, v.z, sz[t]);
            }
        }
        base = nbase; ct = nt; ca = na; cc = nc; cd = nd;
    }

    // ---- per-wave reduction over the 8 groups (conflict-free writes) ----
    // Writer lane L=(8g+s) holds bin 8s+q in reg q. Round A: regs q=0..3 at
    // slot q*64+L (stride-16B across lanes -> conflict-free). Reader lane
    // l<32 (s=l&7, q=l>>3) sums slots q*64+8g+s over g (4-way max).
#pragma unroll
    for (int q = 0; q < 4; q++)
        s_stage[wv][q * 64 + lane] = make_float4(cnt[q], sx[q], sy[q], sz[q]);
    __syncthreads();
    if (lane < 32) {
        int s = lane & 7, q = lane >> 3;
        float4 ra = make_float4(0.0f, 0.0f, 0.0f, 0.0f);
#pragma unroll
        for (int gg = 0; gg < 8; gg++) {
            float4 p = s_stage[wv][q * 64 + (gg << 3) + s];
            ra.x += p.x; ra.y += p.y; ra.z += p.z; ra.w += p.w;
        }
        s_red[wv][(s << 3) + q] = ra;
    }
    __syncthreads();
    // Round B: regs q=4..7 -> bins 8s+q+4
#pragma unroll
    for (int q = 0; q < 4; q++)
        s_stage[wv][q * 64 + lane] = make_float4(cnt[q + 4], sx[q + 4], sy[q + 4], sz[q + 4]);
    __syncthreads();
    if (lane < 32) {
        int s = lane & 7, q = lane >> 3;
        float4 rb = make_float4(0.0f, 0.0f, 0.0f, 0.0f);
#pragma unroll
        for (int gg = 0; gg < 8; gg++) {
            float4 p = s_stage[wv][q * 64 + (gg << 3) + s];
            rb.x += p.x; rb.y += p.y; rb.z += p.z; rb.w += p.w;
        }
        s_red[wv][(s << 3) + q + 4] = rb;
    }
    __syncthreads();

    // flush bg staging buffer: one global atomic per block, coalesced copy
    unsigned nloc = s_bgn < (unsigned)BGBUF ? s_bgn : (unsigned)BGBUF;
    if (tid == 0) s_base = atomicAdd(bgc, nloc);
    __syncthreads();
    {
        unsigned base3 = s_base * 3u;
        unsigned lim3 = (unsigned)maxbg * 3u;
        for (unsigned i = tid; i < nloc * 3u; i += blockDim.x) {
            if (base3 + i < lim3) bgl[base3 + i] = s_bgbuf[i];
        }
    }

    // cross-wave reduce + block-level global atomics; derive h255/h0 algebraically
    if (tid < NINST) {
        float c = 0.0f, x = 0.0f, y = 0.0f, z = 0.0f;
#pragma unroll
        for (int w = 0; w < P1_WAVES; w++) {
            float4 r = s_red[w][tid];
            c += r.x; x += r.y; y += r.z; z += r.w;
        }
        float s3 = x + y + z;
        atomicAdd(&g[OFF_CNT + tid], c);
        atomicAdd(&g[OFF_SUM + tid * 3 + 0], x);
        atomicAdd(&g[OFF_SUM + tid * 3 + 1], y);
        atomicAdd(&g[OFF_SUM + tid * 3 + 2], z);
        atomicAdd(&g[OFF_H255 + tid], 763.5f * c - s3 + s_corr255[tid]);
        if (tid == 0) atomicAdd(&g[OFF_H0], s3 - 1.5f * c + s_corr0);
    }

    // tail pixels (N % 4): direct global accumulation, exact huber
    if (blockIdx.x == 0 && tid < (N & 3)) {
        int i = (M << 2) + tid;
        float t = bt[i], x = bp[i], y = bp[N + i], z = bp[2 * N + i];
        int lab = (int)(t * 0.25f + 0.5f);
        atomicAdd(&g[OFF_CNT + lab], 1.0f);
        atomicAdd(&g[OFF_SUM + lab * 3 + 0], x);
        atomicAdd(&g[OFF_SUM + lab * 3 + 1], y);
        atomicAdd(&g[OFF_SUM + lab * 3 + 2], z);
        atomicAdd(&g[OFF_H255 + lab], huber1(x, 255.f) + huber1(y, 255.f) + huber1(z, 255.f));
        if (lab == 0) {
            atomicAdd(&g[OFF_H0], huber1(x, 0.f) + huber1(y, 0.f) + huber1(z, 0.f));
            unsigned gi = atomicAdd(bgc, 1u);
            if ((int)gi < maxbg) {
                bgl[(size_t)gi * 3 + 0] = x;
                bgl[(size_t)gi * 3 + 1] = y;
                bgl[(size_t)gi * 3 + 2] = z;
            }
        }
    }
}

// Merged pass 2+3. Block role by blockIdx.x:
//  [0, P2_GX):        sep0 partial (streaming over all pixels, vs mean0)
//  [P2_GX, P2_GX+P3B): sep_k partials (bg-pixel list vs all 64 means)
// Overlaps the small latency-bound pass3 under pass2's streaming.
__global__ void k_pass23(const float* __restrict__ pred, const float* __restrict__ targ,
                         const float* __restrict__ acc, const float* __restrict__ bglist,
                         const unsigned* __restrict__ bgcnt, float* __restrict__ p2part,
                         float* __restrict__ p3part, int maxbg, int N) {
    __shared__ float s_w[16];
    __shared__ float s_px[P3_TILE * 3];
    __shared__ float s_part[16][NINST];
    int tid = threadIdx.x;
    int b = blockIdx.y;
    const float* g = acc + (size_t)b * ACC_STRIDE;

    if (blockIdx.x < P2_GX) {
        // ---------------- pass2 role ----------------
        float safe0 = fmaxf(g[OFF_CNT + 0], 1.0f);
        float m0x = g[OFF_SUM + 0] / safe0;
        float m0y = g[OFF_SUM + 1] / safe0;
        float m0z = g[OFF_SUM + 2] / safe0;

        const float* base_p = pred + (size_t)b * 3 * N;
        const float* base_t = targ + (size_t)b * 3 * N;
        const float4* p0 = (const float4*)(base_p);
        const float4* p1 = (const float4*)(base_p + N);
        const float4* p2 = (const float4*)(base_p + 2 * N);
        const float4* t0 = (const float4*)(base_t);

        float local = 0.0f;
        int M = N >> 2;
        for (int i = blockIdx.x * blockDim.x + tid; i < M; i += P2_GX * blockDim.x) {
            float4 t = t0[i], a = p0[i], c = p1[i], d = p2[i];
            float ts[4] = {t.x, t.y, t.z, t.w};
            float xs[4] = {a.x, a.y, a.z, a.w};
            float ys[4] = {c.x, c.y, c.z, c.w};
            float zs[4] = {d.x, d.y, d.z, d.w};
#pragma unroll
            for (int j = 0; j < 4; j++) {
                float dx = xs[j] - m0x, dy = ys[j] - m0y, dz = zs[j] - m0z;
                float D = dx * dx + dy * dy + dz * dz;
                float m = (ts[j] > 2.0f) ? LAMBDA_SEP : 0.0f;   // non-bg iff t>=4
                local = fmaf(m, __builtin_amdgcn_rcpf(1.0f + D), local);
            }
        }
        if (blockIdx.x == 0) {
            for (int i = (M << 2) + tid; i < N; i += blockDim.x) {
                float dx = base_p[i] - m0x, dy = base_p[N + i] - m0y, dz = base_p[2 * N + i] - m0z;
                float D = dx * dx + dy * dy + dz * dz;
                float m = (base_t[i] > 2.0f) ? LAMBDA_SEP : 0.0f;
                local = fmaf(m, __builtin_amdgcn_rcpf(1.0f + D), local);
            }
        }
#pragma unroll
        for (int o = 32; o > 0; o >>= 1) local += __shfl_down(local, o, 64);
        int wv = tid >> 6;
        if ((tid & 63) == 0) s_w[wv] = local;
        __syncthreads();
        if (tid == 0) {
            float s = 0.0f;
            for (int i = 0; i < (P23_THREADS >> 6); i++) s += s_w[i];
            p2part[(size_t)b * P2_GX + blockIdx.x] = s;
        }
    } else {
        // ---------------- pass3 role ----------------
        int bx = blockIdx.x - P2_GX;
        int lane = tid & 63;
        int wv = tid >> 6;
        // lane's own mean (k = lane); k=0 result ignored by k_final
        float safe = fmaxf(g[OFF_CNT + lane], 1.0f);
        float mx = g[OFF_SUM + lane * 3 + 0] / safe;
        float my = g[OFF_SUM + lane * 3 + 1] / safe;
        float mz = g[OFF_SUM + lane * 3 + 2] / safe;

        int nb = min((int)bgcnt[(size_t)b * CNT_STRIDE], maxbg);
        const float* bgl = bglist + (size_t)b * maxbg * 3;

        float lacc = 0.0f;
        int ntiles = (nb + P3_TILE - 1) / P3_TILE;
        for (int tile = bx; tile < ntiles; tile += P3B) {
            int base = tile * P3_TILE;
            int cnt = min(P3_TILE, nb - base);           // pixels in this tile
            __syncthreads();
            for (int i = tid; i < cnt * 3; i += blockDim.x) s_px[i] = bgl[(size_t)base * 3 + i];
            __syncthreads();
            // wave wv handles pixels [wv*64, wv*64+64) of the tile
            int lim = cnt - wv * 64;
            lim = lim < 0 ? 0 : (lim > 64 ? 64 : lim);
            const float* px = &s_px[wv * 64 * 3];
            for (int j = 0; j < lim; j++) {
                float x = px[j * 3 + 0];                 // broadcast: all lanes same addr
                float y = px[j * 3 + 1];
                float z = px[j * 3 + 2];
                float dx = x - mx, dy = y - my, dz = z - mz;
                float D = dx * dx + dy * dy + dz * dz;
                lacc += LAMBDA_SEP * __builtin_amdgcn_rcpf(1.0f + D);
            }
        }
        s_part[wv][lane] = lacc;
        __syncthreads();
        if (tid < NINST) {
            float s = 0.0f;
#pragma unroll
            for (int w = 0; w < 16; w++) s += s_part[w][tid];
            p3part[((size_t)b * P3B + bx) * NINST + tid] = s;
        }
    }
}

// Pass 4: final per-image loss + batch mean. 1 block, 64 threads.
__global__ void k_final(const float* __restrict__ acc, const float* __restrict__ p2part,
                        const float* __restrict__ p3part, const unsigned char* __restrict__ nobg,
                        float* __restrict__ out, int N, int B) {
    int tid = threadIdx.x;  // 0..63
    float total = 0.0f;
    for (int b = 0; b < B; b++) {
        const float* g = acc + (size_t)b * ACC_STRIDE;
        float c = g[OFF_CNT + tid];
        float c0 = g[OFF_CNT + 0];
        bool incl = (c > 0.0f);
        if (tid == 0 && nobg[b] != 0) incl = false;
        float safe = fmaxf(c, 1.0f);
        float var = (tid == 0 ? g[OFF_H0] : g[OFF_H255 + tid]) / (3.0f * safe);
        // wave-parallel sep0 sum (2 entries per lane, reduce to lane 0)
        float s2 = p2part[(size_t)b * P2_GX + tid] + p2part[(size_t)b * P2_GX + NINST + tid];
#pragma unroll
        for (int o = 32; o > 0; o >>= 1) s2 += __shfl_down(s2, o, 64);
        float sepnum;
        if (tid == 0) {
            sepnum = s2;
        } else {
            float s = 0.0f;
#pragma unroll
            for (int j = 0; j < P3B; j++) s += p3part[((size_t)b * P3B + j) * NINST + tid];
            sepnum = s;
        }
        float denom = (tid == 0) ? fmaxf((float)N - c0, 1.0f) : fmaxf(c0, 1.0f);
        float sep = sepnum / denom;
        float w = 10.0f / sqrtf(safe);
        float term = incl ? (var + w * sep) : 0.0f;
        float cnt = incl ? 1.0f : 0.0f;
#pragma unroll
        for (int o = 32; o > 0; o >>= 1) {
            term += __shfl_down(term, o, 64);
            cnt += __shfl_down(cnt, o, 64);
        }
        if (tid == 0) total += term / fmaxf(cnt, 1.0f);
    }
    if (tid == 0) out[0] = total / (float)B;
}

extern "C" void kernel_launch(void* const* d_in, const int* in_sizes, int n_in,
                              void* d_out, int out_size, void* d_ws, size_t ws_size,
                              hipStream_t stream) {
    const float* pred = (const float*)d_in[0];
    const float* targ = (const float*)d_in[1];
    const unsigned char* nobg = (const unsigned char*)d_in[2];
    float* out = (float*)d_out;

    int B = in_sizes[2];            // no_bg has B elements
    int N = in_sizes[0] / (3 * B);  // pixels per image

    // ws layout
    float* acc = (float*)d_ws;
    size_t acc_bytes = (size_t)B * ACC_STRIDE * sizeof(float);
    unsigned* bgcnt = (unsigned*)((char*)d_ws + acc_bytes);          // B counters, stride CNT_STRIDE
    size_t head = acc_bytes + 4096;                                  // zeroed region
    float* p2part = (float*)((char*)d_ws + head);
    size_t p2_bytes = (size_t)B * P2_GX * sizeof(float);
    float* p3part = p2part + (size_t)B * P2_GX;
    size_t p3_bytes = (size_t)B * P3B * NINST * sizeof(float);
    size_t list_off = head + p2_bytes + p3_bytes;
    list_off = (list_off + 255) & ~(size_t)255;
    float* bglist = (float*)((char*)d_ws + list_off);

    int maxbg = 0;
    if (ws_size > list_off) {
        size_t cap = (ws_size - list_off) / ((size_t)B * 3 * sizeof(float));
        maxbg = (int)(cap < (size_t)131072 ? cap : (size_t)131072);
    }

    hipMemsetAsync(d_ws, 0, head, stream);  // zero accumulators + bg counters

    dim3 g1(P1_GX, B);
    k_pass1<<<g1, dim3(P1_THREADS), 0, stream>>>(pred, targ, acc, bgcnt, bglist, maxbg, N);
    dim3 g23(P2_GX + P3B, B);
    k_pass23<<<g23, dim3(P23_THREADS), 0, stream>>>(pred, targ, acc, bglist, bgcnt,
                                                    p2part, p3part, maxbg, N);
    k_final<<<dim3(1), dim3(64), 0, stream>>>(acc, p2part, p3part, nobg, out, N, B);
}